// Round 12
// baseline (120.703 us; speedup 1.0000x reference)
//
#include <hip/hip_runtime.h>
#include <hip/hip_bf16.h>

#define LATN 512
#define FINN 256
#define FOUTN 256
#define NB 16
#define HH 64
#define WW 64

typedef __attribute__((ext_vector_type(8))) short bf16x8;
typedef __attribute__((ext_vector_type(4))) float f32x4;
typedef __attribute__((ext_vector_type(16))) float f32x16;
typedef __attribute__((ext_vector_type(4))) int i32x4;

// ------- workspace byte offsets -------
#define WS_ZERO   0           // 256 B
#define WS_MW2    4096        // 256*256*4 = 262144
#define WS_DCO    266240      // 16*256*4  = 16384
#define WS_SNORM  282624      // 16*256*4  = 16384
#define WS_WFMT   299008      // 4*294912  = 1179648
#define WS_XM     1478656     // 16*2097152 = 33554432
// style ping-pong buffers ALIAS the xm region (dead until xcvt runs):
#define WS_HA     (WS_XM)            // 16*512*4
#define WS_HB     (WS_XM + 32768)    // 16*512*4
#define WS_STY    (WS_XM + 65536)    // 16*256*4
// xm layout  : [b][chunk(8)][pos(4096)][slot(4)] granules of 16B (8 bf16 ch), slot = iq ^ sigma(h,w)
// wfmt layout: [obi(4)][chunk(8)][tap(9)][ol(64)][slot(4)] granules, slot = iq ^ ((ol>>1)&3)

// ================= weight prep: swizzled wfmt + mw2 + zerobuf =================
__global__ void weight_prep_kernel(const float* __restrict__ weight,
                                   __hip_bfloat16* __restrict__ wfmt,
                                   float* __restrict__ mw2sum,
                                   float* __restrict__ zerobuf) {
    __shared__ float red[256];
    int o = blockIdx.x, t = threadIdx.x;
    if (o == 0 && t < 64) zerobuf[t] = 0.f;
    const float* wrow = weight + ((size_t)o * FINN + t) * 9;
    float wv[9];
    float mx = 0.f;
    #pragma unroll
    for (int k = 0; k < 9; ++k) { wv[k] = wrow[k]; mx = fmaxf(mx, fabsf(wv[k])); }
    red[t] = mx;
    __syncthreads();
    for (int k = 128; k > 0; k >>= 1) {
        if (t < k) red[t] = fmaxf(red[t], red[t + k]);
        __syncthreads();
    }
    float scale = (1.0f / 48.0f) / red[0];
    int obi = o >> 6, ol = o & 63, ch = t >> 5, il = t & 31;
    int slot = (il >> 3) ^ ((ol >> 1) & 3);
    char* basep = (char*)wfmt + (size_t)obi * 294912 + (size_t)ch * 36864
                + (size_t)ol * 64 + slot * 16 + (il & 7) * 2;
    float s2 = 0.f;
    #pragma unroll
    for (int tap = 0; tap < 9; ++tap) {
        float m = wv[tap] * scale;
        s2 += m * m;
        *(__hip_bfloat16*)(basep + tap * 4096) = __float2bfloat16(m);
    }
    mw2sum[(size_t)o * FINN + t] = s2;
}

// ================= style MLP layer (parallel over j across blocks) =================
__global__ __launch_bounds__(256) void style_layer_kernel(
    const float* __restrict__ in, const float* __restrict__ w,
    const float* __restrict__ bias, float* __restrict__ out,
    int in_dim_v4, int out_dim, float scale, int do_lrelu) {
    int t = threadIdx.x;
    int jl = t >> 4, kl = t & 15;
    int j = blockIdx.x * 16 + jl;
    int b = blockIdx.y;
    const float4* inr = (const float4*)(in + (size_t)b * (in_dim_v4 * 4));
    const float4* wr  = (const float4*)(w + (size_t)j * (in_dim_v4 * 4));
    float sum = 0.f;
    #pragma unroll 4
    for (int kb = kl; kb < in_dim_v4; kb += 16) {
        float4 wv = wr[kb], iv = inr[kb];
        sum += wv.x * iv.x + wv.y * iv.y + wv.z * iv.z + wv.w * iv.w;
    }
    #pragma unroll
    for (int off = 8; off >= 1; off >>= 1)
        sum += __shfl_xor(sum, off, 16);
    if (kl == 0) {
        float v = sum * scale + bias[j];
        if (do_lrelu && v < 0.f) v *= 0.2f;
        out[(size_t)b * out_dim + j] = v;
    }
}

// ================= fused inf-norm + dcoef =================
__global__ __launch_bounds__(256) void norm_dcoef_kernel(
    const float* __restrict__ sty, const float* __restrict__ mw2,
    float* __restrict__ snorm, float* __restrict__ dco) {
    __shared__ float red[256];
    __shared__ float s2[256];
    int b = blockIdx.x, t = threadIdx.x;
    float v = sty[(size_t)b * FINN + t];
    red[t] = fabsf(v);
    __syncthreads();
    for (int k = 128; k > 0; k >>= 1) {
        if (t < k) red[t] = fmaxf(red[t], red[t + k]);
        __syncthreads();
    }
    float sv = v / red[0];
    snorm[(size_t)b * FINN + t] = sv;
    s2[t] = sv * sv;
    __syncthreads();
    const float4* m2 = (const float4*)(mw2 + (size_t)t * FINN);
    const float4* sq = (const float4*)s2;
    float sum = 0.f;
    #pragma unroll 8
    for (int kb = 0; kb < 64; ++kb) {
        float4 a = m2[kb], xq = sq[kb];
        sum += a.x * xq.x + a.y * xq.y + a.z * xq.z + a.w * xq.w;
    }
    dco[(size_t)b * FOUTN + t] = rsqrtf(sum + 1e-8f);
}

// ================= x NCHW fp32 -> swizzled chunk-major bf16 xm =================
__global__ __launch_bounds__(256) void xcvt_kernel(const float* __restrict__ x,
                                                   const float* __restrict__ sn,
                                                   char* __restrict__ xm) {
    __shared__ float tile[64][65];
    int h = blockIdx.x, b = blockIdx.y;
    int t = threadIdx.x;
    int wl_ = t & 63, ig = t >> 6;
    char* xmb = xm + (size_t)b * 2097152;
    for (int icb = 0; icb < 4; ++icb) {
        if (icb) __syncthreads();
        #pragma unroll
        for (int p = 0; p < 16; ++p) {
            int i_l = p * 4 + ig;
            int i = icb * 64 + i_l;
            tile[i_l][wl_] = x[((size_t)(b * FINN + i)) * 4096 + h * 64 + wl_]
                             * sn[(size_t)b * FINN + i];
        }
        __syncthreads();
        #pragma unroll
        for (int rep = 0; rep < 2; ++rep) {
            int g = rep * 256 + t;     // 0..511
            int w = g >> 3, q8 = g & 7;
            int chunk = icb * 2 + (q8 >> 2), iq = q8 & 3;
            int slot = iq ^ (((h + 1) + ((w + 1) >> 1)) & 3);
            short tmp[8];
            #pragma unroll
            for (int j = 0; j < 8; ++j) {
                __hip_bfloat16 hb = __float2bfloat16(tile[q8 * 8 + j][w]);
                tmp[j] = *(short*)&hb;
            }
            char* dst = xmb + (size_t)chunk * 262144 + (size_t)(h * 64 + w) * 64 + slot * 16;
            *(bf16x8*)dst = *(bf16x8*)tmp;
        }
    }
}

// ================= global_load_lds helper =================
__device__ __forceinline__ void gl_lds16(const void* g, void* l) {
    __builtin_amdgcn_global_load_lds(
        (const __attribute__((address_space(1))) unsigned int*)g,
        (__attribute__((address_space(3))) unsigned int*)l, 16, 0, 0);
}

// ================= MFMA conv: 4-wave blocks, 2 blocks/CU, 32x32x16 MFMA =================
// grid (8 htile, 4 obi, 16 b) = 512 blocks, 256 threads (4 waves).
// Block: 8 output rows (2/wave) x 64 o x 64 w. Wave tile = 2 o-tiles x 4 sp-tiles
// of 32x32, acc = 8 x f32x16 = 128 regs. 12 ds_read_b128 : 16 MFMA32 per tap
// (same LDS traffic as 16x16 version, +21% MFMA rate: m119 8.07 vs 4.85 cyc).
__global__ __launch_bounds__(256, 2) void mconv_kernel(
    const char* __restrict__ xm, const char* __restrict__ wfmt,
    const float* __restrict__ dco, float* __restrict__ y) {
    __shared__ char xs[42240];   // 10 rows x 66 cols x 64B, swizzled slots
    __shared__ char wl[36864];   // [tap 9][o 64][slot 4] granules

    int t = threadIdx.x;
    int lane = t & 63;
    int wid = t >> 6;            // 0..3
    int h0 = blockIdx.x * 8;
    int obi = blockIdx.y;
    int b = blockIdx.z;

    // zero halo columns (c=0,65) for rows 0..9; never staged
    if (t < 80) {
        int r = t >> 3, sub = t & 7;
        int col = (sub >> 2) * 65, slot = sub & 3;
        *(i32x4*)(xs + ((r * 66 + col) * 4 + slot) * 16) = (i32x4){0, 0, 0, 0};
    }
    // zero out-of-range full rows (r=0 at htile 0; r=9 at htile 7); staging skips them
    if (h0 == 0) {
        int e = t;  // 256 threads, 256 granules
        *(i32x4*)(xs + ((0 * 66 + 1 + (e >> 2)) * 4 + (e & 3)) * 16) = (i32x4){0, 0, 0, 0};
    }
    if (h0 == 56) {
        int e = t;
        *(i32x4*)(xs + ((9 * 66 + 1 + (e >> 2)) * 4 + (e & 3)) * 16) = (i32x4){0, 0, 0, 0};
    }

    // x staging: 40 issues/chunk (10 rows x 4 quarters), 10 per wave.
    const char* xmb = xm + (size_t)b * 2097152 + lane * 16;
    unsigned xoff[10], xdst[10];
    #pragma unroll
    for (int q = 0; q < 10; ++q) {
        int idx = wid * 10 + q;
        int r = idx >> 2, quarter = idx & 3;
        int gh = h0 - 1 + r;
        bool v = (gh >= 0) && (gh < HH);
        xoff[q] = (unsigned)__builtin_amdgcn_readfirstlane(
            v ? (int)((gh * 64 + quarter * 16) * 64) : (int)0xFFFFFFFF);
        xdst[q] = (unsigned)__builtin_amdgcn_readfirstlane(
            (int)((r * 66 + 1) * 64 + quarter * 1024));
    }
    // w staging: 36 issues/chunk, 9 per wave
    const char* wlane = wfmt + (size_t)obi * 294912 + lane * 16;

    f32x16 acc[2][4] = {};    // [ot][sp = rr*2+wt]
    int l31 = lane & 31, lh = lane >> 5;

    for (int ch = 0; ch < 8; ++ch) {
        // ---- stage x + w for this chunk ----
        const char* xch = xmb + (size_t)ch * 262144;
        #pragma unroll
        for (int q = 0; q < 10; ++q)
            if (xoff[q] != 0xFFFFFFFFu) gl_lds16(xch + xoff[q], xs + xdst[q]);
        const char* wch = wlane + (size_t)ch * 36864;
        #pragma unroll
        for (int q = 0; q < 9; ++q)
            gl_lds16(wch + (wid + q * 4) * 1024, wl + (wid + q * 4) * 1024);
        asm volatile("s_waitcnt vmcnt(0) lgkmcnt(0)" ::: "memory");
        __builtin_amdgcn_s_barrier();
        __builtin_amdgcn_sched_barrier(0);

        // ---- compute: 9 taps, 2 k-halves each, staged lgkm waits ----
        #pragma unroll
        for (int kh = 0; kh < 3; ++kh) {
            #pragma unroll
            for (int kw = 0; kw < 3; ++kw) {
                int tap = kh * 3 + kw;
                bf16x8 wa[2][2], xb[4][2];   // [.][h]
                #pragma unroll
                for (int h = 0; h < 2; ++h) {
                    int iq = h * 2 + lh;
                    #pragma unroll
                    for (int ot = 0; ot < 2; ++ot) {
                        int o_l = ot * 32 + l31;
                        wa[ot][h] = *(const bf16x8*)(
                            wl + tap * 4096 + o_l * 64 + ((iq ^ ((o_l >> 1) & 3)) << 4));
                    }
                    #pragma unroll
                    for (int rr = 0; rr < 2; ++rr)
                        #pragma unroll
                        for (int wt = 0; wt < 2; ++wt) {
                            int pos = (wid * 2 + kh + rr) * 66 + kw + wt * 32 + l31;
                            xb[rr * 2 + wt][h] = *(const bf16x8*)(
                                xs + pos * 64 + ((iq ^ ((pos >> 1) & 3)) << 4));
                        }
                }
                __builtin_amdgcn_sched_barrier(0);
                asm volatile("s_waitcnt lgkmcnt(6)" ::: "memory");  // h=0 set ready
                __builtin_amdgcn_sched_barrier(0);
                __builtin_amdgcn_s_setprio(1);
                #pragma unroll
                for (int ot = 0; ot < 2; ++ot)
                    #pragma unroll
                    for (int sp = 0; sp < 4; ++sp)
                        acc[ot][sp] = __builtin_amdgcn_mfma_f32_32x32x16_bf16(
                            wa[ot][0], xb[sp][0], acc[ot][sp], 0, 0, 0);
                __builtin_amdgcn_s_setprio(0);
                __builtin_amdgcn_sched_barrier(0);
                asm volatile("s_waitcnt lgkmcnt(0)" ::: "memory");  // h=1 set ready
                __builtin_amdgcn_sched_barrier(0);
                __builtin_amdgcn_s_setprio(1);
                #pragma unroll
                for (int ot = 0; ot < 2; ++ot)
                    #pragma unroll
                    for (int sp = 0; sp < 4; ++sp)
                        acc[ot][sp] = __builtin_amdgcn_mfma_f32_32x32x16_bf16(
                            wa[ot][1], xb[sp][1], acc[ot][sp], 0, 0, 0);
                __builtin_amdgcn_s_setprio(0);
            }
        }

        __builtin_amdgcn_s_barrier();   // release xs/wl for next chunk's stage
        __builtin_amdgcn_sched_barrier(0);
    }

    // epilogue: demod + store. C/D layout: col=lane&31, row=(reg&3)+8*(reg>>2)+4*(lane>>5)
    const float* dcb = dco + (size_t)b * FOUTN + obi * 64;
    #pragma unroll
    for (int ot = 0; ot < 2; ++ot) {
        #pragma unroll
        for (int reg = 0; reg < 16; ++reg) {
            int o_l = ot * 32 + (reg & 3) + 8 * (reg >> 2) + 4 * lh;
            float d = dcb[o_l];
            float* yo = y + (((size_t)b * FOUTN + obi * 64 + o_l) * HH) * WW;
            #pragma unroll
            for (int rr = 0; rr < 2; ++rr) {
                int row = h0 + wid * 2 + rr;
                #pragma unroll
                for (int wt = 0; wt < 2; ++wt)
                    yo[row * 64 + wt * 32 + l31] = acc[ot][rr * 2 + wt][reg] * d;
            }
        }
    }
}

extern "C" void kernel_launch(void* const* d_in, const int* in_sizes, int n_in,
                              void* d_out, int out_size, void* d_ws, size_t ws_size,
                              hipStream_t stream) {
    const float* x      = (const float*)d_in[0];
    const float* lat    = (const float*)d_in[1];
    const float* weight = (const float*)d_in[2];
    const float* wsm    = (const float*)d_in[3];
    const float* bsm    = (const float*)d_in[4];
    const float* wff    = (const float*)d_in[5];
    const float* bff    = (const float*)d_in[6];
    float* y = (float*)d_out;

    char* base = (char*)d_ws;
    float* zerobuf = (float*)(base + WS_ZERO);
    float* mw2     = (float*)(base + WS_MW2);
    float* dco     = (float*)(base + WS_DCO);
    float* snorm   = (float*)(base + WS_SNORM);
    __hip_bfloat16* wfmt = (__hip_bfloat16*)(base + WS_WFMT);
    char* xm       = base + WS_XM;
    float* hA      = (float*)(base + WS_HA);
    float* hB      = (float*)(base + WS_HB);
    float* sty     = (float*)(base + WS_STY);

    const float eq = 0.044194173824159216f;  // 1/sqrt(512)

    weight_prep_kernel<<<FOUTN, 256, 0, stream>>>(weight, wfmt, mw2, zerobuf);
    style_layer_kernel<<<dim3(LATN / 16, NB), 256, 0, stream>>>(
        lat, wsm + 0 * (size_t)LATN * LATN, bsm + 0 * LATN, hA, LATN / 4, LATN, eq, 1);
    style_layer_kernel<<<dim3(LATN / 16, NB), 256, 0, stream>>>(
        hA, wsm + 1 * (size_t)LATN * LATN, bsm + 1 * LATN, hB, LATN / 4, LATN, eq, 1);
    style_layer_kernel<<<dim3(LATN / 16, NB), 256, 0, stream>>>(
        hB, wsm + 2 * (size_t)LATN * LATN, bsm + 2 * LATN, hA, LATN / 4, LATN, eq, 1);
    style_layer_kernel<<<dim3(LATN / 16, NB), 256, 0, stream>>>(
        hA, wsm + 3 * (size_t)LATN * LATN, bsm + 3 * LATN, hB, LATN / 4, LATN, eq, 1);
    style_layer_kernel<<<dim3(FINN / 16, NB), 256, 0, stream>>>(
        hB, wff, bff, sty, LATN / 4, FINN, 1.0f, 0);
    norm_dcoef_kernel<<<NB, 256, 0, stream>>>(sty, mw2, snorm, dco);
    xcvt_kernel<<<dim3(HH, NB), 256, 0, stream>>>(x, snorm, xm);
    mconv_kernel<<<dim3(8, 4, NB), 256, 0, stream>>>(xm, (const char*)wfmt, dco, y);
}

// Round 13
// 119.332 us; speedup vs baseline: 1.0115x; 1.0115x over previous
//
#include <hip/hip_runtime.h>
#include <hip/hip_bf16.h>

#define LATN 512
#define FINN 256
#define FOUTN 256
#define NB 16
#define HH 64
#define WW 64

typedef __attribute__((ext_vector_type(8))) short bf16x8;
typedef __attribute__((ext_vector_type(4))) float f32x4;
typedef __attribute__((ext_vector_type(4))) int i32x4;

// ------- workspace byte offsets -------
#define WS_MW2    4096        // 256*256*4 = 262144
#define WS_DCO    266240      // 16*256*4  = 16384
#define WS_SNORM  282624      // 16*256*4  = 16384
#define WS_WFMT   299008      // 4*294912  = 1179648
#define WS_XM     1478656     // 16*2097152 = 33554432
// style ping-pong buffers ALIAS the xm region (dead until xcvt runs):
#define WS_HA     (WS_XM)            // 16*512*4
#define WS_HB     (WS_XM + 32768)    // 16*512*4
// xm layout  : [b][chunk(8)][pos(4096)][slot(4)] granules of 16B (8 bf16 ch), slot = iq ^ sigma(h,w)
// wfmt layout: [obi(4)][chunk(8)][tap(9)][ol(64)][slot(4)] granules, slot = iq ^ ((ol>>1)&3)

// ================= fused: weight prep (256 blk) + style layer 1 (512 blk) =================
__global__ __launch_bounds__(256) void wprep_style1_kernel(
    const float* __restrict__ weight, __hip_bfloat16* __restrict__ wfmt,
    float* __restrict__ mw2sum,
    const float* __restrict__ lat, const float* __restrict__ w1,
    const float* __restrict__ b1, float* __restrict__ hA) {
    __shared__ float red[256];
    int bx = blockIdx.x, t = threadIdx.x;
    if (bx < 512) {
        // ---- style layer 1: hA[b][j] = lrelu(lat[b]·w1[j]*eq + b1[j]) ----
        const float eq = 0.044194173824159216f;
        int jl = t >> 4, kl = t & 15;
        int jblk = bx & 31, b = bx >> 5;
        int j = jblk * 16 + jl;
        const float4* inr = (const float4*)(lat + (size_t)b * LATN);
        const float4* wr  = (const float4*)(w1 + (size_t)j * LATN);
        float sum = 0.f;
        #pragma unroll 4
        for (int kb = kl; kb < 128; kb += 16) {
            float4 wv = wr[kb], iv = inr[kb];
            sum += wv.x * iv.x + wv.y * iv.y + wv.z * iv.z + wv.w * iv.w;
        }
        #pragma unroll
        for (int off = 8; off >= 1; off >>= 1)
            sum += __shfl_xor(sum, off, 16);
        if (kl == 0) {
            float v = sum * eq + b1[j];
            if (v < 0.f) v *= 0.2f;
            hA[(size_t)b * LATN + j] = v;
        }
    } else {
        // ---- weight prep ----
        int o = bx - 512;
        const float* wrow = weight + ((size_t)o * FINN + t) * 9;
        float wv[9];
        float mx = 0.f;
        #pragma unroll
        for (int k = 0; k < 9; ++k) { wv[k] = wrow[k]; mx = fmaxf(mx, fabsf(wv[k])); }
        red[t] = mx;
        __syncthreads();
        for (int k = 128; k > 0; k >>= 1) {
            if (t < k) red[t] = fmaxf(red[t], red[t + k]);
            __syncthreads();
        }
        float scale = (1.0f / 48.0f) / red[0];
        int obi = o >> 6, ol = o & 63, ch = t >> 5, il = t & 31;
        int slot = (il >> 3) ^ ((ol >> 1) & 3);
        char* basep = (char*)wfmt + (size_t)obi * 294912 + (size_t)ch * 36864
                    + (size_t)ol * 64 + slot * 16 + (il & 7) * 2;
        float s2 = 0.f;
        #pragma unroll
        for (int tap = 0; tap < 9; ++tap) {
            float m = wv[tap] * scale;
            s2 += m * m;
            *(__hip_bfloat16*)(basep + tap * 4096) = __float2bfloat16(m);
        }
        mw2sum[(size_t)o * FINN + t] = s2;
    }
}

// ================= style MLP layer (parallel over j across blocks) =================
__global__ __launch_bounds__(256) void style_layer_kernel(
    const float* __restrict__ in, const float* __restrict__ w,
    const float* __restrict__ bias, float* __restrict__ out,
    int in_dim_v4, int out_dim, float scale, int do_lrelu) {
    int t = threadIdx.x;
    int jl = t >> 4, kl = t & 15;
    int j = blockIdx.x * 16 + jl;
    int b = blockIdx.y;
    const float4* inr = (const float4*)(in + (size_t)b * (in_dim_v4 * 4));
    const float4* wr  = (const float4*)(w + (size_t)j * (in_dim_v4 * 4));
    float sum = 0.f;
    #pragma unroll 4
    for (int kb = kl; kb < in_dim_v4; kb += 16) {
        float4 wv = wr[kb], iv = inr[kb];
        sum += wv.x * iv.x + wv.y * iv.y + wv.z * iv.z + wv.w * iv.w;
    }
    #pragma unroll
    for (int off = 8; off >= 1; off >>= 1)
        sum += __shfl_xor(sum, off, 16);
    if (kl == 0) {
        float v = sum * scale + bias[j];
        if (do_lrelu && v < 0.f) v *= 0.2f;
        out[(size_t)b * out_dim + j] = v;
    }
}

// ================= fused final linear + inf-norm + dcoef (one block per b) =================
__global__ __launch_bounds__(256) void final_norm_dcoef_kernel(
    const float* __restrict__ hB, const float* __restrict__ wf,
    const float* __restrict__ bf, const float* __restrict__ mw2,
    float* __restrict__ snorm, float* __restrict__ dco) {
    __shared__ float lin[512];
    __shared__ float stys[256];
    __shared__ float red[256];
    __shared__ float s2[256];
    int b = blockIdx.x, t = threadIdx.x;
    lin[t] = hB[(size_t)b * LATN + t];
    lin[t + 256] = hB[(size_t)b * LATN + 256 + t];
    __syncthreads();
    // final linear 512->256: 16 passes of 16-lane-group dots (same pattern as style_layer)
    int jl = t >> 4, kl = t & 15;
    const float4* iv = (const float4*)lin;
    #pragma unroll
    for (int jp = 0; jp < 16; ++jp) {
        int j = jp * 16 + jl;
        const float4* wr = (const float4*)(wf + (size_t)j * LATN);
        float sum = 0.f;
        #pragma unroll
        for (int kb = kl; kb < 128; kb += 16) {
            float4 wv = wr[kb], vv = iv[kb];
            sum += wv.x * vv.x + wv.y * vv.y + wv.z * vv.z + wv.w * vv.w;
        }
        #pragma unroll
        for (int off = 8; off >= 1; off >>= 1)
            sum += __shfl_xor(sum, off, 16);
        if (kl == 0) stys[j] = sum + bf[j];
    }
    __syncthreads();
    // inf-norm
    float v = stys[t];
    red[t] = fabsf(v);
    __syncthreads();
    for (int k = 128; k > 0; k >>= 1) {
        if (t < k) red[t] = fmaxf(red[t], red[t + k]);
        __syncthreads();
    }
    float sv = v / red[0];
    snorm[(size_t)b * FINN + t] = sv;
    s2[t] = sv * sv;
    __syncthreads();
    // dcoef
    const float4* m2 = (const float4*)(mw2 + (size_t)t * FINN);
    const float4* sq = (const float4*)s2;
    float sum = 0.f;
    #pragma unroll 8
    for (int kb = 0; kb < 64; ++kb) {
        float4 a = m2[kb], xq = sq[kb];
        sum += a.x * xq.x + a.y * xq.y + a.z * xq.z + a.w * xq.w;
    }
    dco[(size_t)b * FOUTN + t] = rsqrtf(sum + 1e-8f);
}

// ================= x NCHW fp32 -> swizzled chunk-major bf16 xm =================
__global__ __launch_bounds__(256) void xcvt_kernel(const float* __restrict__ x,
                                                   const float* __restrict__ sn,
                                                   char* __restrict__ xm) {
    __shared__ float tile[64][65];
    int h = blockIdx.x, b = blockIdx.y;
    int t = threadIdx.x;
    int wl_ = t & 63, ig = t >> 6;
    char* xmb = xm + (size_t)b * 2097152;
    for (int icb = 0; icb < 4; ++icb) {
        if (icb) __syncthreads();
        #pragma unroll
        for (int p = 0; p < 16; ++p) {
            int i_l = p * 4 + ig;
            int i = icb * 64 + i_l;
            tile[i_l][wl_] = x[((size_t)(b * FINN + i)) * 4096 + h * 64 + wl_]
                             * sn[(size_t)b * FINN + i];
        }
        __syncthreads();
        #pragma unroll
        for (int rep = 0; rep < 2; ++rep) {
            int g = rep * 256 + t;     // 0..511
            int w = g >> 3, q8 = g & 7;
            int chunk = icb * 2 + (q8 >> 2), iq = q8 & 3;
            int slot = iq ^ (((h + 1) + ((w + 1) >> 1)) & 3);
            short tmp[8];
            #pragma unroll
            for (int j = 0; j < 8; ++j) {
                __hip_bfloat16 hb = __float2bfloat16(tile[q8 * 8 + j][w]);
                tmp[j] = *(short*)&hb;
            }
            char* dst = xmb + (size_t)chunk * 262144 + (size_t)(h * 64 + w) * 64 + slot * 16;
            *(bf16x8*)dst = *(bf16x8*)tmp;
        }
    }
}

// ================= global_load_lds helper =================
__device__ __forceinline__ void gl_lds16(const void* g, void* l) {
    __builtin_amdgcn_global_load_lds(
        (const __attribute__((address_space(1))) unsigned int*)g,
        (__attribute__((address_space(3))) unsigned int*)l, 16, 0, 0);
}

// ================= MFMA conv: 4-wave blocks, 2 blocks/CU for overlap (R11 proven) ========
// grid (8 htile, 4 obi, 16 b) = 512 blocks, 256 threads (4 waves).
// Block: 8 output rows (2/wave) x 64 o x 64 w. LDS = 42.2K(xs) + 36.9K(wl) = 79.1KB
// -> 2 independent blocks/CU whose barriers interleave: one block's MFMA phase
// overlaps the other's stage/LDS-read phase (cross-block pipelining, m97-style).
__global__ __launch_bounds__(256, 2) void mconv_kernel(
    const char* __restrict__ xm, const char* __restrict__ wfmt,
    const float* __restrict__ dco, float* __restrict__ y) {
    __shared__ char xs[42240];   // 10 rows x 66 cols x 64B, swizzled slots
    __shared__ char wl[36864];   // [tap 9][o 64][slot 4] granules

    int t = threadIdx.x;
    int lane = t & 63;
    int wid = t >> 6;            // 0..3
    int h0 = blockIdx.x * 8;
    int obi = blockIdx.y;
    int b = blockIdx.z;

    // zero halo columns (c=0,65) for rows 0..9; never staged
    if (t < 80) {
        int r = t >> 3, sub = t & 7;
        int col = (sub >> 2) * 65, slot = sub & 3;
        *(i32x4*)(xs + ((r * 66 + col) * 4 + slot) * 16) = (i32x4){0, 0, 0, 0};
    }
    // zero out-of-range full rows (r=0 at htile 0; r=9 at htile 7); staging skips them
    if (h0 == 0) {
        int e = t;  // 256 threads, 256 granules
        *(i32x4*)(xs + ((0 * 66 + 1 + (e >> 2)) * 4 + (e & 3)) * 16) = (i32x4){0, 0, 0, 0};
    }
    if (h0 == 56) {
        int e = t;
        *(i32x4*)(xs + ((9 * 66 + 1 + (e >> 2)) * 4 + (e & 3)) * 16) = (i32x4){0, 0, 0, 0};
    }

    // x staging: 40 issues/chunk (10 rows x 4 quarters), 10 per wave.
    // Wave-uniform offsets -> SGPRs via readfirstlane; invalid rows = sentinel.
    const char* xmb = xm + (size_t)b * 2097152 + lane * 16;
    unsigned xoff[10], xdst[10];
    #pragma unroll
    for (int q = 0; q < 10; ++q) {
        int idx = wid * 10 + q;
        int r = idx >> 2, quarter = idx & 3;
        int gh = h0 - 1 + r;
        bool v = (gh >= 0) && (gh < HH);
        xoff[q] = (unsigned)__builtin_amdgcn_readfirstlane(
            v ? (int)((gh * 64 + quarter * 16) * 64) : (int)0xFFFFFFFF);
        xdst[q] = (unsigned)__builtin_amdgcn_readfirstlane(
            (int)((r * 66 + 1) * 64 + quarter * 1024));
    }
    // w staging: 36 issues/chunk, 9 per wave
    const char* wlane = wfmt + (size_t)obi * 294912 + lane * 16;

    f32x4 acc[4][8] = {};
    int l15 = lane & 15, lg = lane >> 4;
    int wfrag = l15 * 64 + ((lg ^ ((l15 >> 1) & 3)) << 4);

    for (int ch = 0; ch < 8; ++ch) {
        // ---- stage x + w for this chunk ----
        const char* xch = xmb + (size_t)ch * 262144;
        #pragma unroll
        for (int q = 0; q < 10; ++q)
            if (xoff[q] != 0xFFFFFFFFu) gl_lds16(xch + xoff[q], xs + xdst[q]);
        const char* wch = wlane + (size_t)ch * 36864;
        #pragma unroll
        for (int q = 0; q < 9; ++q)
            gl_lds16(wch + (wid + q * 4) * 1024, wl + (wid + q * 4) * 1024);
        asm volatile("s_waitcnt vmcnt(0) lgkmcnt(0)" ::: "memory");
        __builtin_amdgcn_s_barrier();
        __builtin_amdgcn_sched_barrier(0);

        // ---- compute: 9 taps, staged lgkm waits within tap ----
        #pragma unroll
        for (int kh = 0; kh < 3; ++kh) {
            #pragma unroll
            for (int kw = 0; kw < 3; ++kw) {
                int tap = kh * 3 + kw;
                int pa = (wid * 2 + kh) * 66 + kw + l15;
                int pb = pa + 66;
                int xa = pa * 64 + ((lg ^ ((pa >> 1) & 3)) << 4);
                int xb = pb * 64 + ((lg ^ ((pb >> 1) & 3)) << 4);
                bf16x8 wf[4], x0[4], x1[4];
                #pragma unroll
                for (int mt = 0; mt < 4; ++mt)
                    wf[mt] = *(const bf16x8*)(wl + tap * 4096 + mt * 1024 + wfrag);
                #pragma unroll
                for (int nt = 0; nt < 4; ++nt)
                    x0[nt] = *(const bf16x8*)(xs + xa + nt * 1024);
                #pragma unroll
                for (int nt = 0; nt < 4; ++nt)
                    x1[nt] = *(const bf16x8*)(xs + xb + nt * 1024);
                __builtin_amdgcn_sched_barrier(0);
                asm volatile("s_waitcnt lgkmcnt(4)" ::: "memory");  // wf + x0 ready
                __builtin_amdgcn_sched_barrier(0);
                __builtin_amdgcn_s_setprio(1);
                #pragma unroll
                for (int mt = 0; mt < 4; ++mt)
                    #pragma unroll
                    for (int nt = 0; nt < 4; ++nt)
                        acc[mt][nt] = __builtin_amdgcn_mfma_f32_16x16x32_bf16(
                            wf[mt], x0[nt], acc[mt][nt], 0, 0, 0);
                __builtin_amdgcn_s_setprio(0);
                __builtin_amdgcn_sched_barrier(0);
                asm volatile("s_waitcnt lgkmcnt(0)" ::: "memory");  // x1 ready
                __builtin_amdgcn_sched_barrier(0);
                __builtin_amdgcn_s_setprio(1);
                #pragma unroll
                for (int mt = 0; mt < 4; ++mt)
                    #pragma unroll
                    for (int nt = 0; nt < 4; ++nt)
                        acc[mt][4 + nt] = __builtin_amdgcn_mfma_f32_16x16x32_bf16(
                            wf[mt], x1[nt], acc[mt][4 + nt], 0, 0, 0);
                __builtin_amdgcn_s_setprio(0);
            }
        }

        __builtin_amdgcn_s_barrier();   // release xs/wl for next chunk's stage
        __builtin_amdgcn_sched_barrier(0);
    }

    // epilogue: demod + store (2 rows per wave)
    const float* dcb = dco + (size_t)b * FOUTN + obi * 64;
    #pragma unroll
    for (int rr = 0; rr < 2; ++rr) {
        float* yb = y + (((size_t)b * FOUTN + obi * 64) * HH + (h0 + wid * 2 + rr)) * WW;
        #pragma unroll
        for (int mt = 0; mt < 4; ++mt) {
            #pragma unroll
            for (int j = 0; j < 4; ++j) {
                int o_l = mt * 16 + lg * 4 + j;
                float d = dcb[o_l];
                #pragma unroll
                for (int n4 = 0; n4 < 4; ++n4)
                    yb[(size_t)o_l * 4096 + n4 * 16 + l15] = acc[mt][rr * 4 + n4][j] * d;
            }
        }
    }
}

extern "C" void kernel_launch(void* const* d_in, const int* in_sizes, int n_in,
                              void* d_out, int out_size, void* d_ws, size_t ws_size,
                              hipStream_t stream) {
    const float* x      = (const float*)d_in[0];
    const float* lat    = (const float*)d_in[1];
    const float* weight = (const float*)d_in[2];
    const float* wsm    = (const float*)d_in[3];
    const float* bsm    = (const float*)d_in[4];
    const float* wff    = (const float*)d_in[5];
    const float* bff    = (const float*)d_in[6];
    float* y = (float*)d_out;

    char* base = (char*)d_ws;
    float* mw2     = (float*)(base + WS_MW2);
    float* dco     = (float*)(base + WS_DCO);
    float* snorm   = (float*)(base + WS_SNORM);
    __hip_bfloat16* wfmt = (__hip_bfloat16*)(base + WS_WFMT);
    char* xm       = base + WS_XM;
    float* hA      = (float*)(base + WS_HA);
    float* hB      = (float*)(base + WS_HB);

    const float eq = 0.044194173824159216f;  // 1/sqrt(512)

    // K1: weight prep (role blocks 512..767) + style layer 1 (role blocks 0..511)
    wprep_style1_kernel<<<768, 256, 0, stream>>>(
        weight, wfmt, mw2, lat, wsm + 0 * (size_t)LATN * LATN, bsm + 0 * LATN, hA);
    // layers 2..4
    style_layer_kernel<<<dim3(LATN / 16, NB), 256, 0, stream>>>(
        hA, wsm + 1 * (size_t)LATN * LATN, bsm + 1 * LATN, hB, LATN / 4, LATN, eq, 1);
    style_layer_kernel<<<dim3(LATN / 16, NB), 256, 0, stream>>>(
        hB, wsm + 2 * (size_t)LATN * LATN, bsm + 2 * LATN, hA, LATN / 4, LATN, eq, 1);
    style_layer_kernel<<<dim3(LATN / 16, NB), 256, 0, stream>>>(
        hA, wsm + 3 * (size_t)LATN * LATN, bsm + 3 * LATN, hB, LATN / 4, LATN, eq, 1);
    // K5: final linear + inf-norm + dcoef, one block per b
    final_norm_dcoef_kernel<<<NB, 256, 0, stream>>>(hB, wff, bff, mw2, snorm, dco);
    // x conversion (overwrites the aliased style buffers — safe now)
    xcvt_kernel<<<dim3(HH, NB), 256, 0, stream>>>(x, snorm, xm);
    // MFMA conv (R11 proven config)
    mconv_kernel<<<dim3(8, 4, NB), 256, 0, stream>>>(xm, (const char*)wfmt, dco, y);
}

// Round 14
// 112.335 us; speedup vs baseline: 1.0745x; 1.0623x over previous
//
#include <hip/hip_runtime.h>
#include <hip/hip_bf16.h>

#define LATN 512
#define FINN 256
#define FOUTN 256
#define NB 16
#define HH 64
#define WW 64

typedef __attribute__((ext_vector_type(8))) short bf16x8;
typedef __attribute__((ext_vector_type(4))) float f32x4;
typedef __attribute__((ext_vector_type(4))) int i32x4;

// ------- workspace byte offsets -------
#define WS_ZERO   0           // 256 B
#define WS_MW2    4096        // 256*256*4 = 262144
#define WS_DCO    266240      // 16*256*4  = 16384
#define WS_SNORM  282624      // 16*256*4  = 16384
#define WS_WFMT   299008      // 4*294912  = 1179648
#define WS_XM     1478656     // 16*2097152 = 33554432
// style ping-pong buffers ALIAS the xm region (dead until xcvt runs):
#define WS_HA     (WS_XM)            // 16*512*4
#define WS_HB     (WS_XM + 32768)    // 16*512*4
#define WS_STY    (WS_XM + 65536)    // 16*256*4
// xm layout  : [b][chunk(8)][pos(4096)][slot(4)] granules of 16B (8 bf16 ch), slot = iq ^ sigma(h,w)
// wfmt layout: [obi(4)][chunk(8)][tap(9)][ol(64)][slot(4)] granules, slot = iq ^ ((ol>>1)&3)

// ================= weight prep: swizzled wfmt + mw2 + zerobuf =================
__global__ void weight_prep_kernel(const float* __restrict__ weight,
                                   __hip_bfloat16* __restrict__ wfmt,
                                   float* __restrict__ mw2sum,
                                   float* __restrict__ zerobuf) {
    __shared__ float red[256];
    int o = blockIdx.x, t = threadIdx.x;
    if (o == 0 && t < 64) zerobuf[t] = 0.f;
    const float* wrow = weight + ((size_t)o * FINN + t) * 9;
    float wv[9];
    float mx = 0.f;
    #pragma unroll
    for (int k = 0; k < 9; ++k) { wv[k] = wrow[k]; mx = fmaxf(mx, fabsf(wv[k])); }
    red[t] = mx;
    __syncthreads();
    for (int k = 128; k > 0; k >>= 1) {
        if (t < k) red[t] = fmaxf(red[t], red[t + k]);
        __syncthreads();
    }
    float scale = (1.0f / 48.0f) / red[0];
    int obi = o >> 6, ol = o & 63, ch = t >> 5, il = t & 31;
    int slot = (il >> 3) ^ ((ol >> 1) & 3);
    char* basep = (char*)wfmt + (size_t)obi * 294912 + (size_t)ch * 36864
                + (size_t)ol * 64 + slot * 16 + (il & 7) * 2;
    float s2 = 0.f;
    #pragma unroll
    for (int tap = 0; tap < 9; ++tap) {
        float m = wv[tap] * scale;
        s2 += m * m;
        *(__hip_bfloat16*)(basep + tap * 4096) = __float2bfloat16(m);
    }
    mw2sum[(size_t)o * FINN + t] = s2;
}

// ================= style MLP layer (parallel over j across blocks) =================
__global__ __launch_bounds__(256) void style_layer_kernel(
    const float* __restrict__ in, const float* __restrict__ w,
    const float* __restrict__ bias, float* __restrict__ out,
    int in_dim_v4, int out_dim, float scale, int do_lrelu) {
    int t = threadIdx.x;
    int jl = t >> 4, kl = t & 15;
    int j = blockIdx.x * 16 + jl;
    int b = blockIdx.y;
    const float4* inr = (const float4*)(in + (size_t)b * (in_dim_v4 * 4));
    const float4* wr  = (const float4*)(w + (size_t)j * (in_dim_v4 * 4));
    float sum = 0.f;
    #pragma unroll 4
    for (int kb = kl; kb < in_dim_v4; kb += 16) {
        float4 wv = wr[kb], iv = inr[kb];
        sum += wv.x * iv.x + wv.y * iv.y + wv.z * iv.z + wv.w * iv.w;
    }
    #pragma unroll
    for (int off = 8; off >= 1; off >>= 1)
        sum += __shfl_xor(sum, off, 16);
    if (kl == 0) {
        float v = sum * scale + bias[j];
        if (do_lrelu && v < 0.f) v *= 0.2f;
        out[(size_t)b * out_dim + j] = v;
    }
}

// ================= fused inf-norm + dcoef =================
__global__ __launch_bounds__(256) void norm_dcoef_kernel(
    const float* __restrict__ sty, const float* __restrict__ mw2,
    float* __restrict__ snorm, float* __restrict__ dco) {
    __shared__ float red[256];
    __shared__ float s2[256];
    int b = blockIdx.x, t = threadIdx.x;
    float v = sty[(size_t)b * FINN + t];
    red[t] = fabsf(v);
    __syncthreads();
    for (int k = 128; k > 0; k >>= 1) {
        if (t < k) red[t] = fmaxf(red[t], red[t + k]);
        __syncthreads();
    }
    float sv = v / red[0];
    snorm[(size_t)b * FINN + t] = sv;
    s2[t] = sv * sv;
    __syncthreads();
    const float4* m2 = (const float4*)(mw2 + (size_t)t * FINN);
    const float4* sq = (const float4*)s2;
    float sum = 0.f;
    #pragma unroll 8
    for (int kb = 0; kb < 64; ++kb) {
        float4 a = m2[kb], xq = sq[kb];
        sum += a.x * xq.x + a.y * xq.y + a.z * xq.z + a.w * xq.w;
    }
    dco[(size_t)b * FOUTN + t] = rsqrtf(sum + 1e-8f);
}

// ================= x NCHW fp32 -> swizzled chunk-major bf16 xm =================
__global__ __launch_bounds__(256) void xcvt_kernel(const float* __restrict__ x,
                                                   const float* __restrict__ sn,
                                                   char* __restrict__ xm) {
    __shared__ float tile[64][65];
    int h = blockIdx.x, b = blockIdx.y;
    int t = threadIdx.x;
    int wl_ = t & 63, ig = t >> 6;
    char* xmb = xm + (size_t)b * 2097152;
    for (int icb = 0; icb < 4; ++icb) {
        if (icb) __syncthreads();
        #pragma unroll
        for (int p = 0; p < 16; ++p) {
            int i_l = p * 4 + ig;
            int i = icb * 64 + i_l;
            tile[i_l][wl_] = x[((size_t)(b * FINN + i)) * 4096 + h * 64 + wl_]
                             * sn[(size_t)b * FINN + i];
        }
        __syncthreads();
        #pragma unroll
        for (int rep = 0; rep < 2; ++rep) {
            int g = rep * 256 + t;     // 0..511
            int w = g >> 3, q8 = g & 7;
            int chunk = icb * 2 + (q8 >> 2), iq = q8 & 3;
            int slot = iq ^ (((h + 1) + ((w + 1) >> 1)) & 3);
            short tmp[8];
            #pragma unroll
            for (int j = 0; j < 8; ++j) {
                __hip_bfloat16 hb = __float2bfloat16(tile[q8 * 8 + j][w]);
                tmp[j] = *(short*)&hb;
            }
            char* dst = xmb + (size_t)chunk * 262144 + (size_t)(h * 64 + w) * 64 + slot * 16;
            *(bf16x8*)dst = *(bf16x8*)tmp;
        }
    }
}

// ================= global_load_lds helper =================
__device__ __forceinline__ void gl_lds16(const void* g, void* l) {
    __builtin_amdgcn_global_load_lds(
        (const __attribute__((address_space(1))) unsigned int*)g,
        (__attribute__((address_space(3))) unsigned int*)l, 16, 0, 0);
}

// ================= MFMA conv: 4-wave blocks, 2 blocks/CU for overlap =================
// grid (8 htile, 4 obi, 16 b) = 512 blocks, 256 threads (4 waves).
// Block: 8 output rows (2/wave) x 64 o x 64 w. LDS = 42.2K(xs) + 36.9K(wl) = 79.1KB
// -> 2 independent blocks/CU whose barriers interleave: one block's MFMA phase
// overlaps the other's stage/LDS-read phase (cross-block pipelining, m97-style).
__global__ __launch_bounds__(256, 2) void mconv_kernel(
    const char* __restrict__ xm, const char* __restrict__ wfmt,
    const float* __restrict__ dco, float* __restrict__ y) {
    __shared__ char xs[42240];   // 10 rows x 66 cols x 64B, swizzled slots
    __shared__ char wl[36864];   // [tap 9][o 64][slot 4] granules

    int t = threadIdx.x;
    int lane = t & 63;
    int wid = t >> 6;            // 0..3
    int h0 = blockIdx.x * 8;
    int obi = blockIdx.y;
    int b = blockIdx.z;

    // zero halo columns (c=0,65) for rows 0..9; never staged
    if (t < 80) {
        int r = t >> 3, sub = t & 7;
        int col = (sub >> 2) * 65, slot = sub & 3;
        *(i32x4*)(xs + ((r * 66 + col) * 4 + slot) * 16) = (i32x4){0, 0, 0, 0};
    }
    // zero out-of-range full rows (r=0 at htile 0; r=9 at htile 7); staging skips them
    if (h0 == 0) {
        int e = t;  // 256 threads, 256 granules
        *(i32x4*)(xs + ((0 * 66 + 1 + (e >> 2)) * 4 + (e & 3)) * 16) = (i32x4){0, 0, 0, 0};
    }
    if (h0 == 56) {
        int e = t;
        *(i32x4*)(xs + ((9 * 66 + 1 + (e >> 2)) * 4 + (e & 3)) * 16) = (i32x4){0, 0, 0, 0};
    }

    // x staging: 40 issues/chunk (10 rows x 4 quarters), 10 per wave.
    // Wave-uniform offsets -> SGPRs via readfirstlane; invalid rows = sentinel.
    const char* xmb = xm + (size_t)b * 2097152 + lane * 16;
    unsigned xoff[10], xdst[10];
    #pragma unroll
    for (int q = 0; q < 10; ++q) {
        int idx = wid * 10 + q;
        int r = idx >> 2, quarter = idx & 3;
        int gh = h0 - 1 + r;
        bool v = (gh >= 0) && (gh < HH);
        xoff[q] = (unsigned)__builtin_amdgcn_readfirstlane(
            v ? (int)((gh * 64 + quarter * 16) * 64) : (int)0xFFFFFFFF);
        xdst[q] = (unsigned)__builtin_amdgcn_readfirstlane(
            (int)((r * 66 + 1) * 64 + quarter * 1024));
    }
    // w staging: 36 issues/chunk, 9 per wave
    const char* wlane = wfmt + (size_t)obi * 294912 + lane * 16;

    f32x4 acc[4][8] = {};
    int l15 = lane & 15, lg = lane >> 4;
    int wfrag = l15 * 64 + ((lg ^ ((l15 >> 1) & 3)) << 4);

    for (int ch = 0; ch < 8; ++ch) {
        // ---- stage x + w for this chunk ----
        const char* xch = xmb + (size_t)ch * 262144;
        #pragma unroll
        for (int q = 0; q < 10; ++q)
            if (xoff[q] != 0xFFFFFFFFu) gl_lds16(xch + xoff[q], xs + xdst[q]);
        const char* wch = wlane + (size_t)ch * 36864;
        #pragma unroll
        for (int q = 0; q < 9; ++q)
            gl_lds16(wch + (wid + q * 4) * 1024, wl + (wid + q * 4) * 1024);
        asm volatile("s_waitcnt vmcnt(0) lgkmcnt(0)" ::: "memory");
        __builtin_amdgcn_s_barrier();
        __builtin_amdgcn_sched_barrier(0);

        // ---- compute: 9 taps, staged lgkm waits within tap ----
        #pragma unroll
        for (int kh = 0; kh < 3; ++kh) {
            #pragma unroll
            for (int kw = 0; kw < 3; ++kw) {
                int tap = kh * 3 + kw;
                int pa = (wid * 2 + kh) * 66 + kw + l15;
                int pb = pa + 66;
                int xa = pa * 64 + ((lg ^ ((pa >> 1) & 3)) << 4);
                int xb = pb * 64 + ((lg ^ ((pb >> 1) & 3)) << 4);
                bf16x8 wf[4], x0[4], x1[4];
                #pragma unroll
                for (int mt = 0; mt < 4; ++mt)
                    wf[mt] = *(const bf16x8*)(wl + tap * 4096 + mt * 1024 + wfrag);
                #pragma unroll
                for (int nt = 0; nt < 4; ++nt)
                    x0[nt] = *(const bf16x8*)(xs + xa + nt * 1024);
                #pragma unroll
                for (int nt = 0; nt < 4; ++nt)
                    x1[nt] = *(const bf16x8*)(xs + xb + nt * 1024);
                __builtin_amdgcn_sched_barrier(0);
                asm volatile("s_waitcnt lgkmcnt(4)" ::: "memory");  // wf + x0 ready
                __builtin_amdgcn_sched_barrier(0);
                __builtin_amdgcn_s_setprio(1);
                #pragma unroll
                for (int mt = 0; mt < 4; ++mt)
                    #pragma unroll
                    for (int nt = 0; nt < 4; ++nt)
                        acc[mt][nt] = __builtin_amdgcn_mfma_f32_16x16x32_bf16(
                            wf[mt], x0[nt], acc[mt][nt], 0, 0, 0);
                __builtin_amdgcn_s_setprio(0);
                __builtin_amdgcn_sched_barrier(0);
                asm volatile("s_waitcnt lgkmcnt(0)" ::: "memory");  // x1 ready
                __builtin_amdgcn_sched_barrier(0);
                __builtin_amdgcn_s_setprio(1);
                #pragma unroll
                for (int mt = 0; mt < 4; ++mt)
                    #pragma unroll
                    for (int nt = 0; nt < 4; ++nt)
                        acc[mt][4 + nt] = __builtin_amdgcn_mfma_f32_16x16x32_bf16(
                            wf[mt], x1[nt], acc[mt][4 + nt], 0, 0, 0);
                __builtin_amdgcn_s_setprio(0);
            }
        }

        __builtin_amdgcn_s_barrier();   // release xs/wl for next chunk's stage
        __builtin_amdgcn_sched_barrier(0);
    }

    // epilogue: demod + store (2 rows per wave)
    const float* dcb = dco + (size_t)b * FOUTN + obi * 64;
    #pragma unroll
    for (int rr = 0; rr < 2; ++rr) {
        float* yb = y + (((size_t)b * FOUTN + obi * 64) * HH + (h0 + wid * 2 + rr)) * WW;
        #pragma unroll
        for (int mt = 0; mt < 4; ++mt) {
            #pragma unroll
            for (int j = 0; j < 4; ++j) {
                int o_l = mt * 16 + lg * 4 + j;
                float d = dcb[o_l];
                #pragma unroll
                for (int n4 = 0; n4 < 4; ++n4)
                    yb[(size_t)o_l * 4096 + n4 * 16 + l15] = acc[mt][rr * 4 + n4][j] * d;
            }
        }
    }
}

extern "C" void kernel_launch(void* const* d_in, const int* in_sizes, int n_in,
                              void* d_out, int out_size, void* d_ws, size_t ws_size,
                              hipStream_t stream) {
    const float* x      = (const float*)d_in[0];
    const float* lat    = (const float*)d_in[1];
    const float* weight = (const float*)d_in[2];
    const float* wsm    = (const float*)d_in[3];
    const float* bsm    = (const float*)d_in[4];
    const float* wff    = (const float*)d_in[5];
    const float* bff    = (const float*)d_in[6];
    float* y = (float*)d_out;

    char* base = (char*)d_ws;
    float* zerobuf = (float*)(base + WS_ZERO);
    float* mw2     = (float*)(base + WS_MW2);
    float* dco     = (float*)(base + WS_DCO);
    float* snorm   = (float*)(base + WS_SNORM);
    __hip_bfloat16* wfmt = (__hip_bfloat16*)(base + WS_WFMT);
    char* xm       = base + WS_XM;
    float* hA      = (float*)(base + WS_HA);
    float* hB      = (float*)(base + WS_HB);
    float* sty     = (float*)(base + WS_STY);

    const float eq = 0.044194173824159216f;  // 1/sqrt(512)

    weight_prep_kernel<<<FOUTN, 256, 0, stream>>>(weight, wfmt, mw2, zerobuf);
    style_layer_kernel<<<dim3(LATN / 16, NB), 256, 0, stream>>>(
        lat, wsm + 0 * (size_t)LATN * LATN, bsm + 0 * LATN, hA, LATN / 4, LATN, eq, 1);
    style_layer_kernel<<<dim3(LATN / 16, NB), 256, 0, stream>>>(
        hA, wsm + 1 * (size_t)LATN * LATN, bsm + 1 * LATN, hB, LATN / 4, LATN, eq, 1);
    style_layer_kernel<<<dim3(LATN / 16, NB), 256, 0, stream>>>(
        hB, wsm + 2 * (size_t)LATN * LATN, bsm + 2 * LATN, hA, LATN / 4, LATN, eq, 1);
    style_layer_kernel<<<dim3(LATN / 16, NB), 256, 0, stream>>>(
        hA, wsm + 3 * (size_t)LATN * LATN, bsm + 3 * LATN, hB, LATN / 4, LATN, eq, 1);
    style_layer_kernel<<<dim3(FINN / 16, NB), 256, 0, stream>>>(
        hB, wff, bff, sty, LATN / 4, FINN, 1.0f, 0);
    norm_dcoef_kernel<<<NB, 256, 0, stream>>>(sty, mw2, snorm, dco);
    xcvt_kernel<<<dim3(HH, NB), 256, 0, stream>>>(x, snorm, xm);
    mconv_kernel<<<dim3(8, 4, NB), 256, 0, stream>>>(xm, (const char*)wfmt, dco, y);
}

// Round 15
// 108.749 us; speedup vs baseline: 1.1099x; 1.0330x over previous
//
#include <hip/hip_runtime.h>
#include <hip/hip_bf16.h>

#define LATN 512
#define FINN 256
#define FOUTN 256
#define NB 16
#define HH 64
#define WW 64

typedef __attribute__((ext_vector_type(8))) short bf16x8;
typedef __attribute__((ext_vector_type(4))) float f32x4;
typedef __attribute__((ext_vector_type(4))) int i32x4;

// ------- workspace byte offsets -------
#define WS_MW2    4096        // 256*256*4 = 262144
#define WS_STY    282624      // 16*256*4  = 16384 (NOT aliased with xm: mconv reads it)
#define WS_WFMT   299008      // 4*294912  = 1179648
#define WS_XM     1478656     // 16*2097152 = 33554432
// style ping-pong buffers ALIAS the xm region (dead before xcvt writes xm):
#define WS_HA     (WS_XM)            // 16*512*4
#define WS_HB     (WS_XM + 32768)    // 16*512*4
// xm layout  : [b][chunk(8)][pos(4096)][slot(4)] granules of 16B (8 bf16 ch), slot = iq ^ sigma(h,w)
// wfmt layout: [obi(4)][chunk(8)][tap(9)][ol(64)][slot(4)] granules, slot = iq ^ ((ol>>1)&3)

// ================= weight prep: swizzled wfmt + mw2 =================
__global__ void weight_prep_kernel(const float* __restrict__ weight,
                                   __hip_bfloat16* __restrict__ wfmt,
                                   float* __restrict__ mw2sum) {
    __shared__ float red[256];
    int o = blockIdx.x, t = threadIdx.x;
    const float* wrow = weight + ((size_t)o * FINN + t) * 9;
    float wv[9];
    float mx = 0.f;
    #pragma unroll
    for (int k = 0; k < 9; ++k) { wv[k] = wrow[k]; mx = fmaxf(mx, fabsf(wv[k])); }
    red[t] = mx;
    __syncthreads();
    for (int k = 128; k > 0; k >>= 1) {
        if (t < k) red[t] = fmaxf(red[t], red[t + k]);
        __syncthreads();
    }
    float scale = (1.0f / 48.0f) / red[0];
    int obi = o >> 6, ol = o & 63, ch = t >> 5, il = t & 31;
    int slot = (il >> 3) ^ ((ol >> 1) & 3);
    char* basep = (char*)wfmt + (size_t)obi * 294912 + (size_t)ch * 36864
                + (size_t)ol * 64 + slot * 16 + (il & 7) * 2;
    float s2 = 0.f;
    #pragma unroll
    for (int tap = 0; tap < 9; ++tap) {
        float m = wv[tap] * scale;
        s2 += m * m;
        *(__hip_bfloat16*)(basep + tap * 4096) = __float2bfloat16(m);
    }
    mw2sum[(size_t)o * FINN + t] = s2;
}

// ================= style MLP layer (parallel over j across blocks) =================
__global__ __launch_bounds__(256) void style_layer_kernel(
    const float* __restrict__ in, const float* __restrict__ w,
    const float* __restrict__ bias, float* __restrict__ out,
    int in_dim_v4, int out_dim, float scale, int do_lrelu) {
    int t = threadIdx.x;
    int jl = t >> 4, kl = t & 15;
    int j = blockIdx.x * 16 + jl;
    int b = blockIdx.y;
    const float4* inr = (const float4*)(in + (size_t)b * (in_dim_v4 * 4));
    const float4* wr  = (const float4*)(w + (size_t)j * (in_dim_v4 * 4));
    float sum = 0.f;
    #pragma unroll 4
    for (int kb = kl; kb < in_dim_v4; kb += 16) {
        float4 wv = wr[kb], iv = inr[kb];
        sum += wv.x * iv.x + wv.y * iv.y + wv.z * iv.z + wv.w * iv.w;
    }
    #pragma unroll
    for (int off = 8; off >= 1; off >>= 1)
        sum += __shfl_xor(sum, off, 16);
    if (kl == 0) {
        float v = sum * scale + bias[j];
        if (do_lrelu && v < 0.f) v *= 0.2f;
        out[(size_t)b * out_dim + j] = v;
    }
}

// ================= x NCHW fp32 -> swizzled chunk-major bf16 xm =================
// inf-norm of sty computed wave-redundantly in-kernel (shfl only, no extra launch)
__global__ __launch_bounds__(256) void xcvt_kernel(const float* __restrict__ x,
                                                   const float* __restrict__ sty,
                                                   char* __restrict__ xm) {
    __shared__ float tile[64][65];
    __shared__ float styl[256];
    int h = blockIdx.x, b = blockIdx.y;
    int t = threadIdx.x;
    int lane = t & 63;
    int wl_ = t & 63, ig = t >> 6;
    const float* styb = sty + (size_t)b * FINN;
    float mxv = 0.f;
    #pragma unroll
    for (int q = 0; q < 4; ++q) mxv = fmaxf(mxv, fabsf(styb[lane + 64 * q]));
    #pragma unroll
    for (int off = 32; off >= 1; off >>= 1) mxv = fmaxf(mxv, __shfl_xor(mxv, off));
    float inv_m = 1.0f / mxv;
    styl[t] = styb[t] * inv_m;
    __syncthreads();
    char* xmb = xm + (size_t)b * 2097152;
    for (int icb = 0; icb < 4; ++icb) {
        if (icb) __syncthreads();
        #pragma unroll
        for (int p = 0; p < 16; ++p) {
            int i_l = p * 4 + ig;
            int i = icb * 64 + i_l;
            tile[i_l][wl_] = x[((size_t)(b * FINN + i)) * 4096 + h * 64 + wl_] * styl[i];
        }
        __syncthreads();
        #pragma unroll
        for (int rep = 0; rep < 2; ++rep) {
            int g = rep * 256 + t;     // 0..511
            int w = g >> 3, q8 = g & 7;
            int chunk = icb * 2 + (q8 >> 2), iq = q8 & 3;
            int slot = iq ^ (((h + 1) + ((w + 1) >> 1)) & 3);
            short tmp[8];
            #pragma unroll
            for (int j = 0; j < 8; ++j) {
                __hip_bfloat16 hb = __float2bfloat16(tile[q8 * 8 + j][w]);
                tmp[j] = *(short*)&hb;
            }
            char* dst = xmb + (size_t)chunk * 262144 + (size_t)(h * 64 + w) * 64 + slot * 16;
            *(bf16x8*)dst = *(bf16x8*)tmp;
        }
    }
}

// ================= global_load_lds helper =================
__device__ __forceinline__ void gl_lds16(const void* g, void* l) {
    __builtin_amdgcn_global_load_lds(
        (const __attribute__((address_space(1))) unsigned int*)g,
        (__attribute__((address_space(3))) unsigned int*)l, 16, 0, 0);
}

// ================= MFMA conv: 4-wave blocks, 2 blocks/CU; dcoef fused in prologue ======
// grid (8 htile, 4 obi, 16 b) = 512 blocks, 256 threads (4 waves).
// Block: 8 output rows (2/wave) x 64 o x 64 w. LDS = 42.2K(xs) + 36.9K(wl) + 256B(dcl)
// -> 2 independent blocks/CU whose barriers interleave (cross-block pipelining).
// dcoef (64 o x 256 i dot) computed in chunk-0 prologue, overlapped with staging.
__global__ __launch_bounds__(256, 2) void mconv_kernel(
    const char* __restrict__ xm, const char* __restrict__ wfmt,
    const float* __restrict__ sty, const float* __restrict__ mw2,
    float* __restrict__ y) {
    __shared__ char xs[42240];   // 10 rows x 66 cols x 64B, swizzled slots
    __shared__ char wl[36864];   // [tap 9][o 64][slot 4] granules
    __shared__ float dcl[64];    // per-local-o demod coefficients

    int t = threadIdx.x;
    int lane = t & 63;
    int wid = t >> 6;            // 0..3
    int h0 = blockIdx.x * 8;
    int obi = blockIdx.y;
    int b = blockIdx.z;

    // zero halo columns (c=0,65) for rows 0..9; never staged
    if (t < 80) {
        int r = t >> 3, sub = t & 7;
        int col = (sub >> 2) * 65, slot = sub & 3;
        *(i32x4*)(xs + ((r * 66 + col) * 4 + slot) * 16) = (i32x4){0, 0, 0, 0};
    }
    // zero out-of-range full rows (r=0 at htile 0; r=9 at htile 7); staging skips them
    if (h0 == 0) {
        int e = t;  // 256 threads, 256 granules
        *(i32x4*)(xs + ((0 * 66 + 1 + (e >> 2)) * 4 + (e & 3)) * 16) = (i32x4){0, 0, 0, 0};
    }
    if (h0 == 56) {
        int e = t;
        *(i32x4*)(xs + ((9 * 66 + 1 + (e >> 2)) * 4 + (e & 3)) * 16) = (i32x4){0, 0, 0, 0};
    }

    // x staging: 40 issues/chunk (10 rows x 4 quarters), 10 per wave.
    // Wave-uniform offsets -> SGPRs via readfirstlane; invalid rows = sentinel.
    const char* xmb = xm + (size_t)b * 2097152 + lane * 16;
    unsigned xoff[10], xdst[10];
    #pragma unroll
    for (int q = 0; q < 10; ++q) {
        int idx = wid * 10 + q;
        int r = idx >> 2, quarter = idx & 3;
        int gh = h0 - 1 + r;
        bool v = (gh >= 0) && (gh < HH);
        xoff[q] = (unsigned)__builtin_amdgcn_readfirstlane(
            v ? (int)((gh * 64 + quarter * 16) * 64) : (int)0xFFFFFFFF);
        xdst[q] = (unsigned)__builtin_amdgcn_readfirstlane(
            (int)((r * 66 + 1) * 64 + quarter * 1024));
    }
    // w staging: 36 issues/chunk, 9 per wave
    const char* wlane = wfmt + (size_t)obi * 294912 + lane * 16;

    f32x4 acc[4][8] = {};
    int l15 = lane & 15, lg = lane >> 4;
    int wfrag = l15 * 64 + ((lg ^ ((l15 >> 1) & 3)) << 4);

    for (int ch = 0; ch < 8; ++ch) {
        // ---- stage x + w for this chunk ----
        const char* xch = xmb + (size_t)ch * 262144;
        #pragma unroll
        for (int q = 0; q < 10; ++q)
            if (xoff[q] != 0xFFFFFFFFu) gl_lds16(xch + xoff[q], xs + xdst[q]);
        const char* wch = wlane + (size_t)ch * 36864;
        #pragma unroll
        for (int q = 0; q < 9; ++q)
            gl_lds16(wch + (wid + q * 4) * 1024, wl + (wid + q * 4) * 1024);

        if (ch == 0) {
            // ---- dcoef, overlapped with in-flight chunk-0 staging ----
            const float* styb = sty + (size_t)b * FINN;
            float mxv = 0.f;
            #pragma unroll
            for (int q = 0; q < 4; ++q) mxv = fmaxf(mxv, fabsf(styb[lane + 64 * q]));
            #pragma unroll
            for (int off = 32; off >= 1; off >>= 1) mxv = fmaxf(mxv, __shfl_xor(mxv, off));
            float inv_m2 = 1.0f / (mxv * mxv);
            int o_l = t >> 2, kl = t & 3;
            const float4* m2r = (const float4*)(mw2 + (size_t)(obi * 64 + o_l) * FINN) + kl * 16;
            const float4* svr = (const float4*)styb + kl * 16;
            float sum = 0.f;
            #pragma unroll
            for (int kb = 0; kb < 16; ++kb) {
                float4 a = m2r[kb], v = svr[kb];
                sum += a.x * v.x * v.x + a.y * v.y * v.y + a.z * v.z * v.z + a.w * v.w * v.w;
            }
            sum += __shfl_xor(sum, 1);
            sum += __shfl_xor(sum, 2);
            if (kl == 0) dcl[o_l] = rsqrtf(sum * inv_m2 + 1e-8f);
        }

        asm volatile("s_waitcnt vmcnt(0) lgkmcnt(0)" ::: "memory");
        __builtin_amdgcn_s_barrier();
        __builtin_amdgcn_sched_barrier(0);

        // ---- compute: 9 taps, staged lgkm waits within tap ----
        #pragma unroll
        for (int kh = 0; kh < 3; ++kh) {
            #pragma unroll
            for (int kw = 0; kw < 3; ++kw) {
                int tap = kh * 3 + kw;
                int pa = (wid * 2 + kh) * 66 + kw + l15;
                int pb = pa + 66;
                int xa = pa * 64 + ((lg ^ ((pa >> 1) & 3)) << 4);
                int xb = pb * 64 + ((lg ^ ((pb >> 1) & 3)) << 4);
                bf16x8 wf[4], x0[4], x1[4];
                #pragma unroll
                for (int mt = 0; mt < 4; ++mt)
                    wf[mt] = *(const bf16x8*)(wl + tap * 4096 + mt * 1024 + wfrag);
                #pragma unroll
                for (int nt = 0; nt < 4; ++nt)
                    x0[nt] = *(const bf16x8*)(xs + xa + nt * 1024);
                #pragma unroll
                for (int nt = 0; nt < 4; ++nt)
                    x1[nt] = *(const bf16x8*)(xs + xb + nt * 1024);
                __builtin_amdgcn_sched_barrier(0);
                asm volatile("s_waitcnt lgkmcnt(4)" ::: "memory");  // wf + x0 ready
                __builtin_amdgcn_sched_barrier(0);
                __builtin_amdgcn_s_setprio(1);
                #pragma unroll
                for (int mt = 0; mt < 4; ++mt)
                    #pragma unroll
                    for (int nt = 0; nt < 4; ++nt)
                        acc[mt][nt] = __builtin_amdgcn_mfma_f32_16x16x32_bf16(
                            wf[mt], x0[nt], acc[mt][nt], 0, 0, 0);
                __builtin_amdgcn_s_setprio(0);
                __builtin_amdgcn_sched_barrier(0);
                asm volatile("s_waitcnt lgkmcnt(0)" ::: "memory");  // x1 ready
                __builtin_amdgcn_sched_barrier(0);
                __builtin_amdgcn_s_setprio(1);
                #pragma unroll
                for (int mt = 0; mt < 4; ++mt)
                    #pragma unroll
                    for (int nt = 0; nt < 4; ++nt)
                        acc[mt][4 + nt] = __builtin_amdgcn_mfma_f32_16x16x32_bf16(
                            wf[mt], x1[nt], acc[mt][4 + nt], 0, 0, 0);
                __builtin_amdgcn_s_setprio(0);
            }
        }

        __builtin_amdgcn_s_barrier();   // release xs/wl for next chunk's stage
        __builtin_amdgcn_sched_barrier(0);
    }

    // epilogue: demod + store (2 rows per wave); dcl written in prologue, synced since
    #pragma unroll
    for (int rr = 0; rr < 2; ++rr) {
        float* yb = y + (((size_t)b * FOUTN + obi * 64) * HH + (h0 + wid * 2 + rr)) * WW;
        #pragma unroll
        for (int mt = 0; mt < 4; ++mt) {
            #pragma unroll
            for (int j = 0; j < 4; ++j) {
                int o_l = mt * 16 + lg * 4 + j;
                float d = dcl[o_l];
                #pragma unroll
                for (int n4 = 0; n4 < 4; ++n4)
                    yb[(size_t)o_l * 4096 + n4 * 16 + l15] = acc[mt][rr * 4 + n4][j] * d;
            }
        }
    }
}

extern "C" void kernel_launch(void* const* d_in, const int* in_sizes, int n_in,
                              void* d_out, int out_size, void* d_ws, size_t ws_size,
                              hipStream_t stream) {
    const float* x      = (const float*)d_in[0];
    const float* lat    = (const float*)d_in[1];
    const float* weight = (const float*)d_in[2];
    const float* wsm    = (const float*)d_in[3];
    const float* bsm    = (const float*)d_in[4];
    const float* wff    = (const float*)d_in[5];
    const float* bff    = (const float*)d_in[6];
    float* y = (float*)d_out;

    char* base = (char*)d_ws;
    float* mw2     = (float*)(base + WS_MW2);
    float* sty     = (float*)(base + WS_STY);
    __hip_bfloat16* wfmt = (__hip_bfloat16*)(base + WS_WFMT);
    char* xm       = base + WS_XM;
    float* hA      = (float*)(base + WS_HA);
    float* hB      = (float*)(base + WS_HB);

    const float eq = 0.044194173824159216f;  // 1/sqrt(512)

    weight_prep_kernel<<<FOUTN, 256, 0, stream>>>(weight, wfmt, mw2);
    style_layer_kernel<<<dim3(LATN / 16, NB), 256, 0, stream>>>(
        lat, wsm + 0 * (size_t)LATN * LATN, bsm + 0 * LATN, hA, LATN / 4, LATN, eq, 1);
    style_layer_kernel<<<dim3(LATN / 16, NB), 256, 0, stream>>>(
        hA, wsm + 1 * (size_t)LATN * LATN, bsm + 1 * LATN, hB, LATN / 4, LATN, eq, 1);
    style_layer_kernel<<<dim3(LATN / 16, NB), 256, 0, stream>>>(
        hB, wsm + 2 * (size_t)LATN * LATN, bsm + 2 * LATN, hA, LATN / 4, LATN, eq, 1);
    style_layer_kernel<<<dim3(LATN / 16, NB), 256, 0, stream>>>(
        hA, wsm + 3 * (size_t)LATN * LATN, bsm + 3 * LATN, hB, LATN / 4, LATN, eq, 1);
    style_layer_kernel<<<dim3(FINN / 16, NB), 256, 0, stream>>>(
        hB, wff, bff, sty, LATN / 4, FINN, 1.0f, 0);
    // x conversion with fused inf-norm (overwrites aliased style ping-pong — safe now)
    xcvt_kernel<<<dim3(HH, NB), 256, 0, stream>>>(x, sty, xm);
    // MFMA conv with fused dcoef
    mconv_kernel<<<dim3(8, 4, NB), 256, 0, stream>>>(xm, (const char*)wfmt, sty, mw2, y);
}